// Round 14
// baseline (287.578 us; speedup 1.0000x reference)
//
#include <hip/hip_runtime.h>
#include <hip/hip_bf16.h>

// out = BN(sum_i conv3x3(roll(x, s_i), W_i)), x[32,128,56,56] fp32, W[8,128,128,3,3].
// Interior = circular 5x5 conv with collapsed weights V (bf16 MFMA implicit GEMM).
// main_kernel fuses: conv (512-px tiles, 8 waves, M2xN4, xs dbuf, A from global),
// border correction (compact corrRow/corrCol), corner add-back (cadd). Border/
// corner blocks fill conv's latency gaps. prep_kernel fuses transpose + W preps.

typedef __attribute__((ext_vector_type(8)))  short s16x8;   // 8 bf16 (4 VGPR)
typedef __attribute__((ext_vector_type(16))) float f32x16;  // MFMA 32x32 accum

__device__ __forceinline__ void gload16(const void* g, void* l) {
    __builtin_amdgcn_global_load_lds(
        (const __attribute__((address_space(1))) unsigned int*)g,
        (__attribute__((address_space(3))) unsigned int*)l, 16, 0, 0);
}

__device__ __forceinline__ unsigned short f2bf(float f) {
    __hip_bfloat16 h = __float2bfloat16(f);
    return *(unsigned short*)&h;
}

// ---------- prep: x->xb bf16 + xcols  |  W -> Ap / U / Uc ----------
__global__ __launch_bounds__(256) void prep_kernel(
    const float* __restrict__ x, const float* __restrict__ W,
    unsigned short* __restrict__ xb, float* __restrict__ xcols,
    unsigned short* __restrict__ Ap, float* __restrict__ U, float* __restrict__ Uc) {
    __shared__ float xt[128][57];
    const int bx = blockIdx.x, t = threadIdx.x;
    const int dxs[8] = {-1, 0, 1, -1, 1, -1, 0, 1};
    const int dys[8] = {-1, -1, -1, 0, 0, 1, 1, 1};
    if (bx < 1792) {
        const int h = bx % 56, n = bx / 56;
        for (int it = 0; it < 28; ++it) {
            int idx = it * 256 + t;             // 7168 = 128c * 56w
            int c = idx / 56, w = idx % 56;
            xt[c][w] = x[(((size_t)n * 128 + c) * 56 + h) * 56 + w];
        }
        __syncthreads();
        for (int it = 0; it < 4; ++it) {
            int unit = it * 256 + t;            // 896 = 56w * 16cu
            if (unit < 896) {
                int w = unit >> 4, cu = unit & 15;
                unsigned short pk[8];
#pragma unroll
                for (int j = 0; j < 8; ++j) pk[j] = f2bf(xt[cu * 8 + j][w]);
                *(uint4*)(xb + ((((size_t)n * 56 + h) * 56 + w) * 128 + cu * 8)) = *(uint4*)pk;
            }
        }
        for (int it = 0; it < 2; ++it) {
            int idx = it * 256 + t;             // 512 = 4 * 128
            int c = idx & 127, w4 = idx >> 7;
            const int wmap[4] = {54, 55, 0, 1};
            xcols[(((size_t)n * 4 + w4) * 56 + h) * 128 + c] = xt[c][wmap[w4]];
        }
        return;
    }
    const int bxw = bx - 1792;
    if (bxw < 1600) {
        int idx = bxw * 256 + t;                // 409600 exact
        int tap = idx % 25, oc = idx / 25, c = oc % 128, o = oc / 128;
        int a = tap / 5, b = tap % 5;
        float s = 0.f;
#pragma unroll
        for (int i = 0; i < 8; ++i) {
            int kh = a - 1 + dxs[i];
            int kw = b - 1 + dys[i];
            if (kh >= 0 && kh < 3 && kw >= 0 && kw < 3)
                s += W[(((size_t)i * 128 + o) * 128 + c) * 9 + kh * 3 + kw];
        }
        int chunk = c >> 4, k = c & 15, ku = k >> 3, j = k & 7, mo = o >> 5;
        size_t off = ((((size_t)chunk * 25 + tap) * 4 + mo) * 64 + (ku * 32 + (o & 31))) * 8 + j;
        Ap[off] = f2bf(s);
    } else if (bxw < 1856) {
        int idx = (bxw - 1600) * 256 + t;       // 65536 exact
        int c = idx % 128, o = (idx / 128) % 128, e = idx / 16384;
        float u[15];
#pragma unroll
        for (int k = 0; k < 15; ++k) u[k] = 0.f;
#pragma unroll
        for (int i = 0; i < 8; ++i) {
            if (e < 2) {
                int kh = (e == 0) ? 0 : 2;
                int hh = (e == 0) ? -1 : 56;
                int sr = (hh - dxs[i] + 56) % 56;
                int r = (e == 0) ? (sr == 54 ? 0 : sr == 55 ? 1 : 2)
                                 : (sr == 55 ? 0 : sr == 0 ? 1 : 2);
#pragma unroll
                for (int kw = 0; kw < 3; ++kw) {
                    int be = kw - 1 - dys[i] + 2;
                    u[r * 5 + be] += W[(((size_t)i * 128 + o) * 128 + c) * 9 + kh * 3 + kw];
                }
            } else {
                int kw = (e == 2) ? 0 : 2;
                int ww = (e == 2) ? -1 : 56;
                int sc = (ww - dys[i] + 56) % 56;
                int r = (e == 2) ? (sc == 54 ? 0 : sc == 55 ? 1 : 2)
                                 : (sc == 55 ? 0 : sc == 0 ? 1 : 2);
#pragma unroll
                for (int kh = 0; kh < 3; ++kh) {
                    int al = kh - 1 - dxs[i] + 2;
                    u[r * 5 + al] += W[(((size_t)i * 128 + o) * 128 + c) * 9 + kh * 3 + kw];
                }
            }
        }
#pragma unroll
        for (int k = 0; k < 15; ++k)
            U[(((size_t)e * 15 + k) * 128 + c) * 128 + o] = u[k];
    } else {
        int idx = (bxw - 1856) * 256 + t;       // 65536 exact
        int c = idx % 128, o = (idx / 128) % 128, cr = idx / 16384;
        int hC = (cr >> 1) ? 55 : 0, wC = (cr & 1) ? 55 : 0;
        int khb = hC ? 2 : 0, kwb = wC ? 2 : 0;
        float v[9];
#pragma unroll
        for (int p = 0; p < 9; ++p) v[p] = 0.f;
#pragma unroll
        for (int i = 0; i < 8; ++i)
            v[(dxs[i] + 1) * 3 + (dys[i] + 1)] = W[(((size_t)i * 128 + o) * 128 + c) * 9 + khb * 3 + kwb];
#pragma unroll
        for (int p = 0; p < 9; ++p)
            Uc[(((size_t)cr * 9 + p) * 128 + c) * 128 + o] = v[p];
    }
}

// ---------- main: conv (bx<7) | border (7<=bx<15) | corner (bx==15) ----------
// conv: 512-px tile, 8 waves = og2 x pg4, M_rep2 x N_rep4; xs dbuf 2x32KB;
// A frags global->VGPR (L1/L2 broadcast across pg waves).
__global__ __launch_bounds__(512, 2) void main_kernel(
    const unsigned short* __restrict__ xb, const unsigned short* __restrict__ Ap,
    const float* __restrict__ x, const float* __restrict__ xcols,
    const float* __restrict__ U, const float* __restrict__ Uc,
    float* __restrict__ out, float* __restrict__ P,
    float* __restrict__ corrRow, float* __restrict__ corrCol,
    float* __restrict__ cadd) {
    __shared__ __align__(16) char smem[66048];
    const int bx = blockIdx.x, n = blockIdx.y;
    const int t = threadIdx.x, wv = t >> 6, lane = t & 63;

    if (bx < 7) {
        // ===== conv (round-12 geometry) =====
        const int tile = bx;
        const int p0 = tile * 512;
        const int hstart = p0 / 56 - 2;
        const int og = wv >> 2, pg = wv & 3;
        int vB[4];
        bool fval[4];
#pragma unroll
        for (int nn = 0; nn < 4; ++nn) {
            int px = p0 + pg * 128 + nn * 32 + (lane & 31);
            fval[nn] = px < 3136;
            if (px > 3135) px = 3135;
            int h = px / 56, w = px % 56;
            vB[nn] = (lane >> 5) * 16384 + ((h - hstart - 2) * 60 + w) * 16;   // bytes
        }
        f32x16 acc[2][4];
#pragma unroll
        for (int mm = 0; mm < 2; ++mm)
#pragma unroll
            for (int nn = 0; nn < 4; ++nn)
#pragma unroll
                for (int r = 0; r < 16; ++r) acc[mm][nn][r] = 0.f;

        const unsigned short* xbn = xb + (size_t)n * 401408;
        const unsigned short* apw = Ap + (size_t)(og * 2) * 512 + lane * 8;

        auto stage_xs = [&](int ch, int buf) {
#pragma unroll
            for (int it = 0; it < 4; ++it) {
                int unit = it * 512 + t;            // 0..2047
                int u = unit >> 10, ph = unit & 1023;
                if (ph > 899) ph = 899;              // pad slots, never read
                int r = ph / 60, wc2 = ph % 60;
                int gh = hstart + r;
                gh += (gh < 0) ? 56 : 0;
                gh -= (gh >= 56) ? 56 : 0;
                int gw = wc2 - 2;
                gw += (gw < 0) ? 56 : 0;
                gw -= (gw >= 56) ? 56 : 0;
                gload16(xbn + (gh * 56 + gw) * 128 + ch * 16 + u * 8,
                        smem + buf * 32768 + (size_t)(it * 512 + wv * 64) * 16);
            }
        };

        stage_xs(0, 0);
        __syncthreads();

#pragma unroll 1
        for (int ch = 0; ch < 8; ++ch) {
            if (ch < 7) stage_xs(ch + 1, (ch + 1) & 1);   // prefetch overlaps compute
            const char* xsBase = (const char*)smem + (ch & 1) * 32768;
            const unsigned short* apc = apw + (size_t)ch * 51200;
#pragma unroll
            for (int tap = 0; tap < 25; ++tap) {
                const int toff = ((tap / 5) * 60 + (tap % 5)) * 16;
                s16x8 a0 = *(const s16x8*)(apc + (size_t)tap * 2048);
                s16x8 a1 = *(const s16x8*)(apc + (size_t)tap * 2048 + 512);
                s16x8 b0 = *(const s16x8*)(xsBase + vB[0] + toff);
                s16x8 b1 = *(const s16x8*)(xsBase + vB[1] + toff);
                s16x8 b2 = *(const s16x8*)(xsBase + vB[2] + toff);
                s16x8 b3 = *(const s16x8*)(xsBase + vB[3] + toff);
                acc[0][0] = __builtin_amdgcn_mfma_f32_32x32x16_bf16(a0, b0, acc[0][0], 0, 0, 0);
                acc[1][0] = __builtin_amdgcn_mfma_f32_32x32x16_bf16(a1, b0, acc[1][0], 0, 0, 0);
                acc[0][1] = __builtin_amdgcn_mfma_f32_32x32x16_bf16(a0, b1, acc[0][1], 0, 0, 0);
                acc[1][1] = __builtin_amdgcn_mfma_f32_32x32x16_bf16(a1, b1, acc[1][1], 0, 0, 0);
                acc[0][2] = __builtin_amdgcn_mfma_f32_32x32x16_bf16(a0, b2, acc[0][2], 0, 0, 0);
                acc[1][2] = __builtin_amdgcn_mfma_f32_32x32x16_bf16(a1, b2, acc[1][2], 0, 0, 0);
                acc[0][3] = __builtin_amdgcn_mfma_f32_32x32x16_bf16(a0, b3, acc[0][3], 0, 0, 0);
                acc[1][3] = __builtin_amdgcn_mfma_f32_32x32x16_bf16(a1, b3, acc[1][3], 0, 0, 0);
            }
            __syncthreads();   // drains prefetch + guards buffer overwrite
        }

        const int slot = (n * 7 + tile) * 4 + pg;
#pragma unroll
        for (int mm = 0; mm < 2; ++mm) {
#pragma unroll
            for (int r = 0; r < 16; ++r) {
                int o = og * 64 + mm * 32 + (r & 3) + ((lane >> 5) << 2) + ((r >> 2) << 3);
                float s = 0.f, q = 0.f;
#pragma unroll
                for (int nn = 0; nn < 4; ++nn) {
                    if (fval[nn]) {
                        float v = acc[mm][nn][r];
                        size_t oi = ((size_t)(n * 128 + o)) * 3136 + (p0 + pg * 128 + nn * 32 + (lane & 31));
                        out[oi] = v;
                        s += v;
                        q = fmaf(v, v, q);
                    }
                }
#pragma unroll
                for (int off = 1; off < 32; off <<= 1) {
                    s += __shfl_xor(s, off);
                    q += __shfl_xor(q, off);
                }
                if ((lane & 31) == 0) {
                    P[((size_t)slot * 2 + 0) * 128 + o] = s;
                    P[((size_t)slot * 2 + 1) * 128 + o] = q;
                }
            }
        }
        return;
    }

    if (bx < 15) {
        // ===== border =====
        float (*xsb)[128][33] = reinterpret_cast<float(*)[128][33]>(smem);             // 50,688 B
        float (*red)[2][64][15] = reinterpret_cast<float(*)[2][64][15]>(smem + 50688); // 15,360 B
        const int idx0 = bx - 7;
        const int e = idx0 >> 1, part = idx0 & 1;
        const int oh = wv & 1, qh = (wv >> 1) & 1, chalf = wv >> 2;
        int rows[3];
        if (e == 0 || e == 2) { rows[0] = 54; rows[1] = 55; rows[2] = 0; }
        else                  { rows[0] = 55; rows[1] = 0;  rows[2] = 1; }
        if (e < 2) {
            for (int it = 0; it < 24; ++it) {
                int idx = it * 512 + t;             // 3*128*32 = 12288
                int m = idx & 31, c = (idx >> 5) & 127, r = idx >> 12;
                int g = part * 28 + m - 2;
                g += (g < 0) ? 56 : 0;
                g -= (g >= 56) ? 56 : 0;
                xsb[r][c][m] = x[(((size_t)n * 128 + c) * 56 + rows[r]) * 56 + g];
            }
        } else {
            int w4[3];
#pragma unroll
            for (int r = 0; r < 3; ++r)
                w4[r] = (rows[r] == 54) ? 0 : (rows[r] == 55) ? 1 : (rows[r] == 0) ? 2 : 3;
            for (int it = 0; it < 24; ++it) {
                int idx = it * 512 + t;
                int c = idx & 127, m = (idx >> 7) & 31, r = idx >> 12;
                int g = part * 28 + m - 2;
                g += (g < 0) ? 56 : 0;
                g -= (g >= 56) ? 56 : 0;
                xsb[r][c][m] = xcols[(((size_t)n * 4 + w4[r]) * 56 + g) * 128 + c];
            }
        }
        __syncthreads();
        const int o = oh * 64 + lane;
        const int pxl = qh * 14;
        float corr[14];
#pragma unroll
        for (int k = 0; k < 14; ++k) corr[k] = 0.f;
#pragma unroll 2
        for (int ci = 0; ci < 64; ++ci) {
            const int c = chalf * 64 + ci;
#pragma unroll
            for (int r = 0; r < 3; ++r) {
                float xl[18];
#pragma unroll
                for (int j = 0; j < 18; ++j) xl[j] = xsb[r][c][pxl + j];
#pragma unroll
                for (int be = 0; be < 5; ++be) {
                    float u = U[(((size_t)e * 15 + r * 5 + be) * 128 + c) * 128 + o];
#pragma unroll
                    for (int k = 0; k < 14; ++k) corr[k] = fmaf(u, xl[k + be], corr[k]);
                }
            }
        }
        if (chalf == 1) {
#pragma unroll
            for (int k = 0; k < 14; ++k) red[qh][oh][lane][k] = corr[k];
        }
        __syncthreads();
        if (chalf == 0) {
#pragma unroll
            for (int k = 0; k < 14; ++k) corr[k] += red[qh][oh][lane][k];
            const int pbase = part * 28 + qh * 14;
            float* dst = (e < 2 ? corrRow + (((size_t)e * 32 + n) * 128 + o) * 56
                                : corrCol + (((size_t)(e - 2) * 32 + n) * 128 + o) * 56) + pbase;
#pragma unroll
            for (int k = 0; k < 14; ++k) dst[k] = corr[k];
        }
        return;
    }

    // ===== corner (bx == 15): all 4 corners for this n =====
    {
        float (*xc)[128] = reinterpret_cast<float(*)[128]>(smem);   // [36][128] = 18,432 B
        for (int it = 0; it < 9; ++it) {
            int idx = it * 512 + t;                 // 4608 exact
            int c = idx & 127, p = (idx >> 7) % 9, cr = idx / 1152;
            int di = p / 3, dj = p % 3;
            int hC = (cr >> 1) ? 55 : 0, wC = (cr & 1) ? 55 : 0;
            int khb = hC ? 2 : 0, kwb = wC ? 2 : 0;
            int hs = (hC + khb - 1 - (di - 1) + 56) % 56;
            int ws = (wC + kwb - 1 - (dj - 1) + 56) % 56;
            int w4 = (ws == 54) ? 0 : (ws == 55) ? 1 : (ws == 0) ? 2 : 3;
            xc[cr * 9 + p][c] = xcols[(((size_t)n * 4 + w4) * 56 + hs) * 128 + c];
        }
        __syncthreads();
        const int cr = t >> 7, o = t & 127;
        float corr = 0.f;
        const float* ucb = Uc + ((size_t)cr * 9 * 128) * 128 + o;
#pragma unroll 4
        for (int pc = 0; pc < 1152; ++pc) {
            int p = pc >> 7, c = pc & 127;
            corr = fmaf(ucb[(size_t)pc * 128], xc[cr * 9 + p][c], corr);
        }
        cadd[(size_t)cr * 4096 + n * 128 + o] = corr;
    }
}

// ---------- finalize: conv partials + exact border stats delta -> scale/shift ----------
__global__ __launch_bounds__(256) void finalize_kernel(
    const float* __restrict__ P, const float* __restrict__ out,
    const float* __restrict__ corrRow, const float* __restrict__ corrCol,
    const float* __restrict__ cadd,
    const float* __restrict__ gamma, const float* __restrict__ beta,
    float* __restrict__ SS) {
    const int c = blockIdx.x, t = threadIdx.x;
    float s = 0.f, q = 0.f;
    for (int sl = t; sl < 896; sl += 256) {
        s += P[((size_t)sl * 2 + 0) * 128 + c];
        q += P[((size_t)sl * 2 + 1) * 128 + c];
    }
    for (int item = t; item < 7040; item += 256) {
        int n = item / 220, bidx = item % 220;
        int h, w;
        if (bidx < 56)       { h = 0;  w = bidx; }
        else if (bidx < 112) { h = 55; w = bidx - 56; }
        else if (bidx < 166) { w = 0;  h = bidx - 111; }   // h in [1,54]
        else                 { w = 55; h = bidx - 165; }
        float d = 0.f;
        if (h == 0)  d -= corrRow[(((size_t)0 * 32 + n) * 128 + c) * 56 + w];
        if (h == 55) d -= corrRow[(((size_t)1 * 32 + n) * 128 + c) * 56 + w];
        if (w == 0)  d -= corrCol[(((size_t)0 * 32 + n) * 128 + c) * 56 + h];
        if (w == 55) d -= corrCol[(((size_t)1 * 32 + n) * 128 + c) * 56 + h];
        if ((h == 0 || h == 55) && (w == 0 || w == 55)) {
            int cr = (h ? 2 : 0) + (w ? 1 : 0);
            d += cadd[(size_t)cr * 4096 + n * 128 + c];
        }
        float old = out[((size_t)(n * 128 + c)) * 3136 + h * 56 + w];
        s += d;
        q += d * d + 2.f * old * d;
    }
    __shared__ float rs[256], rq[256];
    rs[t] = s; rq[t] = q;
    __syncthreads();
    for (int st = 128; st > 0; st >>= 1) {
        if (t < st) { rs[t] += rs[t + st]; rq[t] += rq[t + st]; }
        __syncthreads();
    }
    if (t == 0) {
        const float inv = 1.f / 100352.f;
        float mean = rs[0] * inv;
        float var  = rq[0] * inv - mean * mean;
        float sc = gamma[c] * rsqrtf(var + 1e-5f);
        SS[c] = sc;
        SS[128 + c] = beta[c] - mean * sc;
    }
}

// ---------- bn_apply: (v + border_delta) * sc + sh, streamed ----------
__global__ __launch_bounds__(256) void bn_apply_kernel(
    float* __restrict__ out, const float* __restrict__ SS,
    const float* __restrict__ corrRow, const float* __restrict__ corrCol,
    const float* __restrict__ cadd) {
    size_t idx = (size_t)blockIdx.x * 256 + threadIdx.x;   // 3,211,264 float4 exact
    int plane = (int)(idx / 784);                          // n*128 + c
    int rem = (int)(idx % 784);
    int h = rem / 14, w4 = (rem % 14) * 4;
    int c = plane & 127, n = plane >> 7;
    float sc = SS[c], sh = SS[128 + c];
    float4 v = ((float4*)out)[idx];
    float d0 = 0.f, d1 = 0.f, d2 = 0.f, d3 = 0.f;
    if (h == 0 || h == 55) {
        int eh = (h == 55) ? 1 : 0;
        const float4 cr4 = *(const float4*)(corrRow + (((size_t)eh * 32 + n) * 128 + c) * 56 + w4);
        d0 -= cr4.x; d1 -= cr4.y; d2 -= cr4.z; d3 -= cr4.w;
    }
    if (w4 == 0)  d0 -= corrCol[(((size_t)0 * 32 + n) * 128 + c) * 56 + h];
    if (w4 == 52) d3 -= corrCol[(((size_t)1 * 32 + n) * 128 + c) * 56 + h];
    if (h == 0 || h == 55) {
        int hb = (h == 55) ? 2 : 0;
        if (w4 == 0)  d0 += cadd[(size_t)(hb + 0) * 4096 + n * 128 + c];
        if (w4 == 52) d3 += cadd[(size_t)(hb + 1) * 4096 + n * 128 + c];
    }
    v.x = fmaf(v.x + d0, sc, sh);
    v.y = fmaf(v.y + d1, sc, sh);
    v.z = fmaf(v.z + d2, sc, sh);
    v.w = fmaf(v.w + d3, sc, sh);
    ((float4*)out)[idx] = v;
}

extern "C" void kernel_launch(void* const* d_in, const int* in_sizes, int n_in,
                              void* d_out, int out_size, void* d_ws, size_t ws_size,
                              hipStream_t stream) {
    const float* x     = (const float*)d_in[0];
    const float* W     = (const float*)d_in[1];
    const float* gamma = (const float*)d_in[2];
    const float* beta  = (const float*)d_in[3];
    float* out = (float*)d_out;

    char* ws = (char*)d_ws;
    unsigned short* xb = (unsigned short*)ws;               // 25,690,112 B
    unsigned short* Ap = (unsigned short*)(ws + 25690112);  //    823,296 B
    float* U       = (float*)(ws + 26513408);               //  3,932,160 B
    float* Uc      = (float*)(ws + 30445568);               //  2,359,296 B
    float* P       = (float*)(ws + 32804864);               //  1,212,416 B
    float* SS      = (float*)(ws + 34017280);               //      1,024 B
    float* xcols   = (float*)(ws + 34018304);               //  3,670,016 B
    float* corrRow = (float*)(ws + 37688320);               //  1,835,008 B
    float* corrCol = (float*)(ws + 39523328);               //  1,835,008 B
    float* cadd    = (float*)(ws + 41358336);               //     65,536 B

    prep_kernel<<<3904, 256, 0, stream>>>(x, W, xb, xcols, Ap, U, Uc);
    main_kernel<<<dim3(16, 32), 512, 0, stream>>>(xb, Ap, x, xcols, U, Uc,
                                                  out, P, corrRow, corrCol, cadd);
    finalize_kernel<<<128, 256, 0, stream>>>(P, out, corrRow, corrCol, cadd, gamma, beta, SS);
    bn_apply_kernel<<<12544, 256, 0, stream>>>(out, SS, corrRow, corrCol, cadd);
}

// Round 15
// 277.700 us; speedup vs baseline: 1.0356x; 1.0356x over previous
//
#include <hip/hip_runtime.h>
#include <hip/hip_bf16.h>

// out = BN(sum_i conv3x3(roll(x, s_i), W_i)), x[32,128,56,56] fp32, W[8,128,128,3,3].
// Interior = circular 5x5 conv with collapsed weights V (bf16 MFMA implicit GEMM).
// main_kernel fuses conv (256-px tiles, 8 waves, M2xN2) + border + corner, with
// CONV-FIRST dispatch order (1-D grid) so the long-pole conv blocks start at t=0
// and short border/corner blocks backfill. s_setprio(1) wraps the MFMA cluster
// (heterogeneous co-resident waves -> scheduler arbitration pays, T5).

typedef __attribute__((ext_vector_type(8)))  short s16x8;   // 8 bf16 (4 VGPR)
typedef __attribute__((ext_vector_type(16))) float f32x16;  // MFMA 32x32 accum

__device__ __forceinline__ void gload16(const void* g, void* l) {
    __builtin_amdgcn_global_load_lds(
        (const __attribute__((address_space(1))) unsigned int*)g,
        (__attribute__((address_space(3))) unsigned int*)l, 16, 0, 0);
}

__device__ __forceinline__ unsigned short f2bf(float f) {
    __hip_bfloat16 h = __float2bfloat16(f);
    return *(unsigned short*)&h;
}

// ---------- prep: x->xb bf16 + xcols  |  W -> Ap / U / Uc ----------
__global__ __launch_bounds__(256) void prep_kernel(
    const float* __restrict__ x, const float* __restrict__ W,
    unsigned short* __restrict__ xb, float* __restrict__ xcols,
    unsigned short* __restrict__ Ap, float* __restrict__ U, float* __restrict__ Uc) {
    __shared__ float xt[128][57];
    const int bx = blockIdx.x, t = threadIdx.x;
    const int dxs[8] = {-1, 0, 1, -1, 1, -1, 0, 1};
    const int dys[8] = {-1, -1, -1, 0, 0, 1, 1, 1};
    if (bx < 1792) {
        const int h = bx % 56, n = bx / 56;
        for (int it = 0; it < 28; ++it) {
            int idx = it * 256 + t;             // 7168 = 128c * 56w
            int c = idx / 56, w = idx % 56;
            xt[c][w] = x[(((size_t)n * 128 + c) * 56 + h) * 56 + w];
        }
        __syncthreads();
        for (int it = 0; it < 4; ++it) {
            int unit = it * 256 + t;            // 896 = 56w * 16cu
            if (unit < 896) {
                int w = unit >> 4, cu = unit & 15;
                unsigned short pk[8];
#pragma unroll
                for (int j = 0; j < 8; ++j) pk[j] = f2bf(xt[cu * 8 + j][w]);
                *(uint4*)(xb + ((((size_t)n * 56 + h) * 56 + w) * 128 + cu * 8)) = *(uint4*)pk;
            }
        }
        for (int it = 0; it < 2; ++it) {
            int idx = it * 256 + t;             // 512 = 4 * 128
            int c = idx & 127, w4 = idx >> 7;
            const int wmap[4] = {54, 55, 0, 1};
            xcols[(((size_t)n * 4 + w4) * 56 + h) * 128 + c] = xt[c][wmap[w4]];
        }
        return;
    }
    const int bxw = bx - 1792;
    if (bxw < 1600) {
        int idx = bxw * 256 + t;                // 409600 exact
        int tap = idx % 25, oc = idx / 25, c = oc % 128, o = oc / 128;
        int a = tap / 5, b = tap % 5;
        float s = 0.f;
#pragma unroll
        for (int i = 0; i < 8; ++i) {
            int kh = a - 1 + dxs[i];
            int kw = b - 1 + dys[i];
            if (kh >= 0 && kh < 3 && kw >= 0 && kw < 3)
                s += W[(((size_t)i * 128 + o) * 128 + c) * 9 + kh * 3 + kw];
        }
        int chunk = c >> 4, k = c & 15, ku = k >> 3, j = k & 7, mo = o >> 5;
        size_t off = ((((size_t)chunk * 25 + tap) * 4 + mo) * 64 + (ku * 32 + (o & 31))) * 8 + j;
        Ap[off] = f2bf(s);
    } else if (bxw < 1856) {
        int idx = (bxw - 1600) * 256 + t;       // 65536 exact
        int c = idx % 128, o = (idx / 128) % 128, e = idx / 16384;
        float u[15];
#pragma unroll
        for (int k = 0; k < 15; ++k) u[k] = 0.f;
#pragma unroll
        for (int i = 0; i < 8; ++i) {
            if (e < 2) {
                int kh = (e == 0) ? 0 : 2;
                int hh = (e == 0) ? -1 : 56;
                int sr = (hh - dxs[i] + 56) % 56;
                int r = (e == 0) ? (sr == 54 ? 0 : sr == 55 ? 1 : 2)
                                 : (sr == 55 ? 0 : sr == 0 ? 1 : 2);
#pragma unroll
                for (int kw = 0; kw < 3; ++kw) {
                    int be = kw - 1 - dys[i] + 2;
                    u[r * 5 + be] += W[(((size_t)i * 128 + o) * 128 + c) * 9 + kh * 3 + kw];
                }
            } else {
                int kw = (e == 2) ? 0 : 2;
                int ww = (e == 2) ? -1 : 56;
                int sc = (ww - dys[i] + 56) % 56;
                int r = (e == 2) ? (sc == 54 ? 0 : sc == 55 ? 1 : 2)
                                 : (sc == 55 ? 0 : sc == 0 ? 1 : 2);
#pragma unroll
                for (int kh = 0; kh < 3; ++kh) {
                    int al = kh - 1 - dxs[i] + 2;
                    u[r * 5 + al] += W[(((size_t)i * 128 + o) * 128 + c) * 9 + kh * 3 + kw];
                }
            }
        }
#pragma unroll
        for (int k = 0; k < 15; ++k)
            U[(((size_t)e * 15 + k) * 128 + c) * 128 + o] = u[k];
    } else {
        int idx = (bxw - 1856) * 256 + t;       // 65536 exact
        int c = idx % 128, o = (idx / 128) % 128, cr = idx / 16384;
        int hC = (cr >> 1) ? 55 : 0, wC = (cr & 1) ? 55 : 0;
        int khb = hC ? 2 : 0, kwb = wC ? 2 : 0;
        float v[9];
#pragma unroll
        for (int p = 0; p < 9; ++p) v[p] = 0.f;
#pragma unroll
        for (int i = 0; i < 8; ++i)
            v[(dxs[i] + 1) * 3 + (dys[i] + 1)] = W[(((size_t)i * 128 + o) * 128 + c) * 9 + khb * 3 + kwb];
#pragma unroll
        for (int p = 0; p < 9; ++p)
            Uc[(((size_t)cr * 9 + p) * 128 + c) * 128 + o] = v[p];
    }
}

// ---------- main: 1-D grid 704, conv-first ----------
// flat <416: conv (tile = flat%13, n = flat/13); 416..671: border; 672..703: corner.
// conv: 256-px tile, 8 waves = og2 x pg4, M_rep2 x N_rep2; xs dbuf 2x20KB;
// A frags global->VGPR.
__global__ __launch_bounds__(512, 4) void main_kernel(
    const unsigned short* __restrict__ xb, const unsigned short* __restrict__ Ap,
    const float* __restrict__ x, const float* __restrict__ xcols,
    const float* __restrict__ U, const float* __restrict__ Uc,
    float* __restrict__ out, float* __restrict__ P,
    float* __restrict__ corrRow, float* __restrict__ corrCol,
    float* __restrict__ cadd) {
    __shared__ __align__(16) char smem[66048];
    const int flat = blockIdx.x;
    const int t = threadIdx.x, wv = t >> 6, lane = t & 63;

    if (flat < 416) {
        // ===== conv =====
        const int tile = flat % 13, n = flat / 13;
        const int p0 = tile * 256;
        const int hstart = p0 / 56 - 2;
        const int og = wv >> 2, pg = wv & 3;
        int vB[2];
        bool fval[2];
#pragma unroll
        for (int nn = 0; nn < 2; ++nn) {
            int px = p0 + pg * 64 + nn * 32 + (lane & 31);
            fval[nn] = px < 3136;
            if (px > 3135) px = 3135;
            int h = px / 56, w = px % 56;
            vB[nn] = (lane >> 5) * 10240 + ((h - hstart - 2) * 60 + w) * 16;   // bytes
        }
        f32x16 acc[2][2];
#pragma unroll
        for (int mm = 0; mm < 2; ++mm)
#pragma unroll
            for (int nn = 0; nn < 2; ++nn)
#pragma unroll
                for (int r = 0; r < 16; ++r) acc[mm][nn][r] = 0.f;

        const unsigned short* xbn = xb + (size_t)n * 401408;
        const unsigned short* apw = Ap + (size_t)(og * 2) * 512 + lane * 8;

        auto stage_xs = [&](int ch, int buf) {
#pragma unroll
            for (int it = 0; it < 3; ++it) {
                int base = it * 512 + wv * 64;      // wave-uniform
                if (base < 1280) {
                    int unit = base + lane;
                    int u = (unit >= 640) ? 1 : 0;
                    int ph = unit - u * 640;
                    if (ph > 599) ph = 599;          // pad slots, never read
                    int r = ph / 60, wc2 = ph % 60;
                    int gh = hstart + r;
                    gh += (gh < 0) ? 56 : 0;
                    gh -= (gh >= 56) ? 56 : 0;
                    int gw = wc2 - 2;
                    gw += (gw < 0) ? 56 : 0;
                    gw -= (gw >= 56) ? 56 : 0;
                    gload16(xbn + (gh * 56 + gw) * 128 + ch * 16 + u * 8,
                            smem + buf * 20480 + (size_t)base * 16);
                }
            }
        };

        stage_xs(0, 0);
        __syncthreads();

#pragma unroll 1
        for (int ch = 0; ch < 8; ++ch) {
            if (ch < 7) stage_xs(ch + 1, (ch + 1) & 1);   // prefetch overlaps compute
            const char* xsBase = (const char*)smem + (ch & 1) * 20480;
            const unsigned short* apc = apw + (size_t)ch * 51200;
            __builtin_amdgcn_s_setprio(1);
#pragma unroll
            for (int tap = 0; tap < 25; ++tap) {
                const int toff = ((tap / 5) * 60 + (tap % 5)) * 16;
                s16x8 a0 = *(const s16x8*)(apc + (size_t)tap * 2048);
                s16x8 a1 = *(const s16x8*)(apc + (size_t)tap * 2048 + 512);
                s16x8 b0 = *(const s16x8*)(xsBase + vB[0] + toff);
                s16x8 b1 = *(const s16x8*)(xsBase + vB[1] + toff);
                acc[0][0] = __builtin_amdgcn_mfma_f32_32x32x16_bf16(a0, b0, acc[0][0], 0, 0, 0);
                acc[1][0] = __builtin_amdgcn_mfma_f32_32x32x16_bf16(a1, b0, acc[1][0], 0, 0, 0);
                acc[0][1] = __builtin_amdgcn_mfma_f32_32x32x16_bf16(a0, b1, acc[0][1], 0, 0, 0);
                acc[1][1] = __builtin_amdgcn_mfma_f32_32x32x16_bf16(a1, b1, acc[1][1], 0, 0, 0);
            }
            __builtin_amdgcn_s_setprio(0);
            __syncthreads();   // drains prefetch + guards buffer overwrite
        }

        // epilogue: store + in-block (pg-reduced) per-channel partials
        float* redc = (float*)smem;               // [2 which][4 pg][128 o] = 4KB
        const int slot = n * 13 + tile;
#pragma unroll
        for (int mm = 0; mm < 2; ++mm) {
#pragma unroll
            for (int r = 0; r < 16; ++r) {
                int o = og * 64 + mm * 32 + (r & 3) + ((lane >> 5) << 2) + ((r >> 2) << 3);
                float s = 0.f, q = 0.f;
#pragma unroll
                for (int nn = 0; nn < 2; ++nn) {
                    if (fval[nn]) {
                        float v = acc[mm][nn][r];
                        size_t oi = ((size_t)(n * 128 + o)) * 3136 + (p0 + pg * 64 + nn * 32 + (lane & 31));
                        out[oi] = v;
                        s += v;
                        q = fmaf(v, v, q);
                    }
                }
#pragma unroll
                for (int off = 1; off < 32; off <<= 1) {
                    s += __shfl_xor(s, off);
                    q += __shfl_xor(q, off);
                }
                if ((lane & 31) == 0) {
                    redc[pg * 128 + o] = s;
                    redc[512 + pg * 128 + o] = q;
                }
            }
        }
        __syncthreads();
        if (t < 256) {
            int o = t & 127, which = t >> 7;
            const float* rb = redc + which * 512;
            P[((size_t)slot * 2 + which) * 128 + o] = rb[o] + rb[128 + o] + rb[256 + o] + rb[384 + o];
        }
        return;
    }

    if (flat < 672) {
        // ===== border =====
        float (*xsb)[128][33] = reinterpret_cast<float(*)[128][33]>(smem);             // 50,688 B
        float (*red)[2][64][15] = reinterpret_cast<float(*)[2][64][15]>(smem + 50688); // 15,360 B
        const int idx0 = flat - 416;
        const int n = idx0 >> 3, sub = idx0 & 7;
        const int e = sub >> 1, part = sub & 1;
        const int oh = wv & 1, qh = (wv >> 1) & 1, chalf = wv >> 2;
        int rows[3];
        if (e == 0 || e == 2) { rows[0] = 54; rows[1] = 55; rows[2] = 0; }
        else                  { rows[0] = 55; rows[1] = 0;  rows[2] = 1; }
        if (e < 2) {
            for (int it = 0; it < 24; ++it) {
                int idx = it * 512 + t;             // 3*128*32 = 12288
                int m = idx & 31, c = (idx >> 5) & 127, r = idx >> 12;
                int g = part * 28 + m - 2;
                g += (g < 0) ? 56 : 0;
                g -= (g >= 56) ? 56 : 0;
                xsb[r][c][m] = x[(((size_t)n * 128 + c) * 56 + rows[r]) * 56 + g];
            }
        } else {
            int w4[3];
#pragma unroll
            for (int r = 0; r < 3; ++r)
                w4[r] = (rows[r] == 54) ? 0 : (rows[r] == 55) ? 1 : (rows[r] == 0) ? 2 : 3;
            for (int it = 0; it < 24; ++it) {
                int idx = it * 512 + t;
                int c = idx & 127, m = (idx >> 7) & 31, r = idx >> 12;
                int g = part * 28 + m - 2;
                g += (g < 0) ? 56 : 0;
                g -= (g >= 56) ? 56 : 0;
                xsb[r][c][m] = xcols[(((size_t)n * 4 + w4[r]) * 56 + g) * 128 + c];
            }
        }
        __syncthreads();
        const int o = oh * 64 + lane;
        const int pxl = qh * 14;
        float corr[14];
#pragma unroll
        for (int k = 0; k < 14; ++k) corr[k] = 0.f;
#pragma unroll 2
        for (int ci = 0; ci < 64; ++ci) {
            const int c = chalf * 64 + ci;
#pragma unroll
            for (int r = 0; r < 3; ++r) {
                float xl[18];
#pragma unroll
                for (int j = 0; j < 18; ++j) xl[j] = xsb[r][c][pxl + j];
#pragma unroll
                for (int be = 0; be < 5; ++be) {
                    float u = U[(((size_t)e * 15 + r * 5 + be) * 128 + c) * 128 + o];
#pragma unroll
                    for (int k = 0; k < 14; ++k) corr[k] = fmaf(u, xl[k + be], corr[k]);
                }
            }
        }
        if (chalf == 1) {
#pragma unroll
            for (int k = 0; k < 14; ++k) red[qh][oh][lane][k] = corr[k];
        }
        __syncthreads();
        if (chalf == 0) {
#pragma unroll
            for (int k = 0; k < 14; ++k) corr[k] += red[qh][oh][lane][k];
            const int pbase = part * 28 + qh * 14;
            float* dst = (e < 2 ? corrRow + (((size_t)e * 32 + n) * 128 + o) * 56
                                : corrCol + (((size_t)(e - 2) * 32 + n) * 128 + o) * 56) + pbase;
#pragma unroll
            for (int k = 0; k < 14; ++k) dst[k] = corr[k];
        }
        return;
    }

    // ===== corner: all 4 corners for this n =====
    {
        const int n = flat - 672;
        float (*xc)[128] = reinterpret_cast<float(*)[128]>(smem);   // [36][128] = 18,432 B
        for (int it = 0; it < 9; ++it) {
            int idx = it * 512 + t;                 // 4608 exact
            int c = idx & 127, p = (idx >> 7) % 9, cr = idx / 1152;
            int di = p / 3, dj = p % 3;
            int hC = (cr >> 1) ? 55 : 0, wC = (cr & 1) ? 55 : 0;
            int khb = hC ? 2 : 0, kwb = wC ? 2 : 0;
            int hs = (hC + khb - 1 - (di - 1) + 56) % 56;
            int ws = (wC + kwb - 1 - (dj - 1) + 56) % 56;
            int w4 = (ws == 54) ? 0 : (ws == 55) ? 1 : (ws == 0) ? 2 : 3;
            xc[cr * 9 + p][c] = xcols[(((size_t)n * 4 + w4) * 56 + hs) * 128 + c];
        }
        __syncthreads();
        const int cr = t >> 7, o = t & 127;
        float corr = 0.f;
        const float* ucb = Uc + ((size_t)cr * 9 * 128) * 128 + o;
#pragma unroll 4
        for (int pc = 0; pc < 1152; ++pc) {
            int p = pc >> 7, c = pc & 127;
            corr = fmaf(ucb[(size_t)pc * 128], xc[cr * 9 + p][c], corr);
        }
        cadd[(size_t)cr * 4096 + n * 128 + o] = corr;
    }
}

// ---------- finalize: conv partials + exact border stats delta -> scale/shift ----------
__global__ __launch_bounds__(256) void finalize_kernel(
    const float* __restrict__ P, const float* __restrict__ out,
    const float* __restrict__ corrRow, const float* __restrict__ corrCol,
    const float* __restrict__ cadd,
    const float* __restrict__ gamma, const float* __restrict__ beta,
    float* __restrict__ SS) {
    const int c = blockIdx.x, t = threadIdx.x;
    float s = 0.f, q = 0.f;
    for (int sl = t; sl < 416; sl += 256) {
        s += P[((size_t)sl * 2 + 0) * 128 + c];
        q += P[((size_t)sl * 2 + 1) * 128 + c];
    }
    for (int item = t; item < 7040; item += 256) {
        int n = item / 220, bidx = item % 220;
        int h, w;
        if (bidx < 56)       { h = 0;  w = bidx; }
        else if (bidx < 112) { h = 55; w = bidx - 56; }
        else if (bidx < 166) { w = 0;  h = bidx - 111; }   // h in [1,54]
        else                 { w = 55; h = bidx - 165; }
        float d = 0.f;
        if (h == 0)  d -= corrRow[(((size_t)0 * 32 + n) * 128 + c) * 56 + w];
        if (h == 55) d -= corrRow[(((size_t)1 * 32 + n) * 128 + c) * 56 + w];
        if (w == 0)  d -= corrCol[(((size_t)0 * 32 + n) * 128 + c) * 56 + h];
        if (w == 55) d -= corrCol[(((size_t)1 * 32 + n) * 128 + c) * 56 + h];
        if ((h == 0 || h == 55) && (w == 0 || w == 55)) {
            int cr = (h ? 2 : 0) + (w ? 1 : 0);
            d += cadd[(size_t)cr * 4096 + n * 128 + c];
        }
        float old = out[((size_t)(n * 128 + c)) * 3136 + h * 56 + w];
        s += d;
        q += d * d + 2.f * old * d;
    }
    __shared__ float rs[256], rq[256];
    rs[t] = s; rq[t] = q;
    __syncthreads();
    for (int st = 128; st > 0; st >>= 1) {
        if (t < st) { rs[t] += rs[t + st]; rq[t] += rq[t + st]; }
        __syncthreads();
    }
    if (t == 0) {
        const float inv = 1.f / 100352.f;
        float mean = rs[0] * inv;
        float var  = rq[0] * inv - mean * mean;
        float sc = gamma[c] * rsqrtf(var + 1e-5f);
        SS[c] = sc;
        SS[128 + c] = beta[c] - mean * sc;
    }
}

// ---------- bn_apply: (v + border_delta) * sc + sh, streamed ----------
__global__ __launch_bounds__(256) void bn_apply_kernel(
    float* __restrict__ out, const float* __restrict__ SS,
    const float* __restrict__ corrRow, const float* __restrict__ corrCol,
    const float* __restrict__ cadd) {
    size_t idx = (size_t)blockIdx.x * 256 + threadIdx.x;   // 3,211,264 float4 exact
    int plane = (int)(idx / 784);                          // n*128 + c
    int rem = (int)(idx % 784);
    int h = rem / 14, w4 = (rem % 14) * 4;
    int c = plane & 127, n = plane >> 7;
    float sc = SS[c], sh = SS[128 + c];
    float4 v = ((float4*)out)[idx];
    float d0 = 0.f, d1 = 0.f, d2 = 0.f, d3 = 0.f;
    if (h == 0 || h == 55) {
        int eh = (h == 55) ? 1 : 0;
        const float4 cr4 = *(const float4*)(corrRow + (((size_t)eh * 32 + n) * 128 + c) * 56 + w4);
        d0 -= cr4.x; d1 -= cr4.y; d2 -= cr4.z; d3 -= cr4.w;
    }
    if (w4 == 0)  d0 -= corrCol[(((size_t)0 * 32 + n) * 128 + c) * 56 + h];
    if (w4 == 52) d3 -= corrCol[(((size_t)1 * 32 + n) * 128 + c) * 56 + h];
    if (h == 0 || h == 55) {
        int hb = (h == 55) ? 2 : 0;
        if (w4 == 0)  d0 += cadd[(size_t)(hb + 0) * 4096 + n * 128 + c];
        if (w4 == 52) d3 += cadd[(size_t)(hb + 1) * 4096 + n * 128 + c];
    }
    v.x = fmaf(v.x + d0, sc, sh);
    v.y = fmaf(v.y + d1, sc, sh);
    v.z = fmaf(v.z + d2, sc, sh);
    v.w = fmaf(v.w + d3, sc, sh);
    ((float4*)out)[idx] = v;
}

extern "C" void kernel_launch(void* const* d_in, const int* in_sizes, int n_in,
                              void* d_out, int out_size, void* d_ws, size_t ws_size,
                              hipStream_t stream) {
    const float* x     = (const float*)d_in[0];
    const float* W     = (const float*)d_in[1];
    const float* gamma = (const float*)d_in[2];
    const float* beta  = (const float*)d_in[3];
    float* out = (float*)d_out;

    char* ws = (char*)d_ws;
    unsigned short* xb = (unsigned short*)ws;               // 25,690,112 B
    unsigned short* Ap = (unsigned short*)(ws + 25690112);  //    823,296 B
    float* U       = (float*)(ws + 26513408);               //  3,932,160 B
    float* Uc      = (float*)(ws + 30445568);               //  2,359,296 B
    float* P       = (float*)(ws + 32804864);               //    425,984 B used
    float* SS      = (float*)(ws + 34017280);               //      1,024 B
    float* xcols   = (float*)(ws + 34018304);               //  3,670,016 B
    float* corrRow = (float*)(ws + 37688320);               //  1,835,008 B
    float* corrCol = (float*)(ws + 39523328);               //  1,835,008 B
    float* cadd    = (float*)(ws + 41358336);               //     65,536 B

    prep_kernel<<<3904, 256, 0, stream>>>(x, W, xb, xcols, Ap, U, Uc);
    main_kernel<<<704, 512, 0, stream>>>(xb, Ap, x, xcols, U, Uc,
                                         out, P, corrRow, corrCol, cadd);
    finalize_kernel<<<128, 256, 0, stream>>>(P, out, corrRow, corrCol, cadd, gamma, beta, SS);
    bn_apply_kernel<<<12544, 256, 0, stream>>>(out, SS, corrRow, corrCol, cadd);
}